// Round 7
// baseline (860.234 us; speedup 1.0000x reference)
//
#include <hip/hip_runtime.h>
#include <hip/hip_fp16.h>

#define D 64
constexpr int TPB = 256;
constexpr int BSHIFT = 8;              // 256 nodes per bucket
typedef unsigned short u16;

// ---------------- histogram of destination degrees ---------------------------
__global__ void hist_kernel(const int* __restrict__ col, int* __restrict__ deg, int E) {
    int e = blockIdx.x * blockDim.x + threadIdx.x;
    if (e < E) atomicAdd(&deg[col[e]], 1);
}

// ---------------- dis[i] = deg>0 ? deg^-0.5 : 0 ------------------------------
__global__ void dis_kernel(const int* __restrict__ deg, float* __restrict__ dis, int N) {
    int i = blockIdx.x * blockDim.x + threadIdx.x;
    if (i < N) {
        int d = deg[i];
        dis[i] = (d > 0) ? rsqrtf((float)d) : 0.0f;
    }
}

// ---------------- scan stage 1: per-block inclusive scan + block sums --------
__global__ void scan1_kernel(const int* __restrict__ deg, int* __restrict__ part,
                             int* __restrict__ bsum, int N) {
    __shared__ int s[TPB];
    int t = threadIdx.x;
    int i = blockIdx.x * TPB + t;
    int v = (i < N) ? deg[i] : 0;
    s[t] = v;
    __syncthreads();
    for (int off = 1; off < TPB; off <<= 1) {
        int x = (t >= off) ? s[t - off] : 0;
        __syncthreads();
        s[t] += x;
        __syncthreads();
    }
    if (i < N) part[i] = s[t];
    if (t == TPB - 1) bsum[blockIdx.x] = s[t];
}

// ---------------- scan stage 2: exclusive scan of block sums (single block) --
__global__ void scan2_kernel(const int* __restrict__ bsum, int* __restrict__ boffs, int nb) {
    __shared__ int s[1024];
    int t = threadIdx.x;
    int v = (t < nb) ? bsum[t] : 0;
    s[t] = v;
    __syncthreads();
    for (int off = 1; off < 1024; off <<= 1) {
        int x = (t >= off) ? s[t - off] : 0;
        __syncthreads();
        s[t] += x;
        __syncthreads();
    }
    if (t < nb) boffs[t] = s[t] - v;   // exclusive
}

// ---------------- scan stage 3: row_ptr = boffs[b] + part[i] - deg[i] --------
__global__ void scan3_kernel(const int* __restrict__ deg, const int* __restrict__ part,
                             const int* __restrict__ boffs, int* __restrict__ row_ptr,
                             int N, int E) {
    int i = blockIdx.x * blockDim.x + threadIdx.x;
    if (i < N) row_ptr[i] = boffs[blockIdx.x] + part[i] - deg[i];
    if (i == 0) row_ptr[N] = E;
}

// ---------------- bucket offsets: boff[b] = row_ptr[min(b*256, N)] -----------
__global__ void boff_kernel(const int* __restrict__ row_ptr, int* __restrict__ boff,
                            int N, int NBUK) {
    int i = blockIdx.x * blockDim.x + threadIdx.x;
    if (i <= NBUK) boff[i] = row_ptr[min(i << BSHIFT, N)];
}

// ---------------- place level 1: scatter (row,col) into 586 bucket regions ---
// Counters padded to one per 64B line to avoid line-lock serialization.
__global__ void place1_kernel(const int* __restrict__ row, const int* __restrict__ col,
                              const int* __restrict__ boff, int* __restrict__ c1,
                              uint2* __restrict__ tmp, int E) {
    int e = blockIdx.x * blockDim.x + threadIdx.x;
    if (e < E) {
        int c = col[e];
        int b = c >> BSHIFT;
        int p = boff[b] + atomicAdd(&c1[b * 16], 1);   // hot padded counter
        tmp[p] = make_uint2((unsigned)row[e], (unsigned)c);
    }
}

// ---------------- place level 2: one block per bucket, LDS cursors -----------
// Reads its bucket's pairs contiguously, places into srow via LDS atomics;
// srow writes confined to the bucket's ~27KB window (single XCD, full lines).
__global__ void place2_kernel(const uint2* __restrict__ tmp, const int* __restrict__ boff,
                              const int* __restrict__ row_ptr, int* __restrict__ srow,
                              int N) {
    __shared__ int lcur[1 << BSHIFT];
    int b = blockIdx.x;
    int base = b << BSHIFT;
    int nn = min(1 << BSHIFT, N - base);
    int t = threadIdx.x;
    if (t < nn) lcur[t] = row_ptr[base + t];
    __syncthreads();
    int start = boff[b], end = boff[b + 1];
    for (int i = start + t; i < end; i += blockDim.x) {
        uint2 e = tmp[i];
        int p = atomicAdd(&lcur[(int)e.y - base], 1);
        srow[p] = (int)e.x;
    }
}

// ---------------- Z0 = fp16(dis ⊙ emb): one thread per element ---------------
__global__ void z0_kernel(const float* __restrict__ emb, const float* __restrict__ dis,
                          u16* __restrict__ z, int n) {
    int i = blockIdx.x * blockDim.x + threadIdx.x;
    if (i < n) {
        float d = dis[i >> 6];            // 64 floats per node
        z[i] = __half_as_ushort(__float2half_rn(d * emb[i]));
    }
}

// ---------------- CSR SpMM: one wave per destination node, lane = dim --------
// (verbatim from the passing round-6 kernel: 8-deep gather pipeline)
template <int MODE, bool WRITE_DST>
__global__ void spmm_kernel(const int* __restrict__ row_ptr, const int* __restrict__ srow,
                            const float* __restrict__ dis,
                            const u16* __restrict__ src, u16* __restrict__ dst,
                            float* __restrict__ out, const float* __restrict__ emb, int N) {
    int wave = (blockIdx.x * blockDim.x + threadIdx.x) >> 6;
    int lane = threadIdx.x & 63;
    if (wave >= N) return;
    int start = row_ptr[wave];
    int end   = row_ptr[wave + 1];
    float acc = 0.0f;
    for (int base = start; base < end; base += 64) {
        int mye = base + lane;
        int rr = (mye < end) ? srow[mye] : 0;   // coalesced edge-index load
        int cnt = min(64, end - base);
        int j = 0;
        for (; j + 8 <= cnt; j += 8) {
            int r0 = __shfl(rr, j + 0);
            int r1 = __shfl(rr, j + 1);
            int r2 = __shfl(rr, j + 2);
            int r3 = __shfl(rr, j + 3);
            int r4 = __shfl(rr, j + 4);
            int r5 = __shfl(rr, j + 5);
            int r6 = __shfl(rr, j + 6);
            int r7 = __shfl(rr, j + 7);
            u16 u0 = src[(size_t)r0 * D + lane];   // 8 independent row gathers
            u16 u1 = src[(size_t)r1 * D + lane];
            u16 u2 = src[(size_t)r2 * D + lane];
            u16 u3 = src[(size_t)r3 * D + lane];
            u16 u4 = src[(size_t)r4 * D + lane];
            u16 u5 = src[(size_t)r5 * D + lane];
            u16 u6 = src[(size_t)r6 * D + lane];
            u16 u7 = src[(size_t)r7 * D + lane];
            acc += __half2float(__ushort_as_half(u0));
            acc += __half2float(__ushort_as_half(u1));
            acc += __half2float(__ushort_as_half(u2));
            acc += __half2float(__ushort_as_half(u3));
            acc += __half2float(__ushort_as_half(u4));
            acc += __half2float(__ushort_as_half(u5));
            acc += __half2float(__ushort_as_half(u6));
            acc += __half2float(__ushort_as_half(u7));
        }
        for (; j < cnt; ++j) {
            int r = __shfl(rr, j);
            acc += __half2float(__ushort_as_half(src[(size_t)r * D + lane]));
        }
    }
    float dc = dis[wave];
    float embs = dc * acc;
    size_t o = (size_t)wave * D + lane;
    if (WRITE_DST) dst[o] = __half_as_ushort(__float2half_rn(dc * embs));
    if (MODE == 0)      out[o] = emb[o] + embs;
    else if (MODE == 1) out[o] += embs;
    else                out[o] = (out[o] + embs) * 0.25f;
}

extern "C" void kernel_launch(void* const* d_in, const int* in_sizes, int n_in,
                              void* d_out, int out_size, void* d_ws, size_t ws_size,
                              hipStream_t stream) {
    const int* edge = (const int*)d_in[0];
    const float* emb = (const float*)d_in[1];
    const int E = in_sizes[0] / 2;       // 4,000,000
    const int N = in_sizes[1] / D;       // 150,000
    float* out = (float*)d_out;

    const int* row = edge;
    const int* col = edge + E;

    const int NBUK = (N + (1 << BSHIFT) - 1) >> BSHIFT;   // 586

    // workspace layout; tmp (32MB) aliases A+B (38.4MB) — tmp dead before z0
    u16*   A       = (u16*)d_ws;                   // N*64 fp16 (Z ping)
    u16*   B       = A + (size_t)N * D;            // N*64 fp16 (Z pong)
    uint2* tmp     = (uint2*)d_ws;                 // E pairs (bucketed edges)
    int*   srow    = (int*)(B + (size_t)N * D);    // E ints (sorted rows)
    int*   row_ptr = srow + E;                     // N+1 ints
    int*   deg     = row_ptr + N + 1;              // N ints
    int*   part    = deg + N;                      // N ints
    float* dis     = (float*)(part + N);           // N floats
    int*   bsum    = (int*)(dis + N);              // nb ints
    const int nb = (N + TPB - 1) / TPB;            // 586
    int*   boffs   = bsum + nb;                    // nb ints (scan block offsets)
    int*   boff    = boffs + nb;                   // NBUK+1 ints (bucket offsets)
    int*   c1      = boff + NBUK + 1;              // NBUK*16 ints (padded cursors)

    const int edge_blocks = (E + TPB - 1) / TPB;
    const int node_blocks = nb;
    const int n = N * D;
    const int z_blocks = (n + TPB - 1) / TPB;
    const int spmm_blocks = (N * 64 + TPB - 1) / TPB;   // 1 wave per node

    // ---- degree + normalization + row_ptr
    hipMemsetAsync(deg, 0, (size_t)N * sizeof(int), stream);
    hist_kernel<<<edge_blocks, TPB, 0, stream>>>(col, deg, E);
    dis_kernel<<<node_blocks, TPB, 0, stream>>>(deg, dis, N);
    scan1_kernel<<<node_blocks, TPB, 0, stream>>>(deg, part, bsum, N);
    scan2_kernel<<<1, 1024, 0, stream>>>(bsum, boffs, nb);
    scan3_kernel<<<node_blocks, TPB, 0, stream>>>(deg, part, boffs, row_ptr, N, E);

    // ---- two-level placement
    boff_kernel<<<(NBUK + TPB) / TPB, TPB, 0, stream>>>(row_ptr, boff, N, NBUK);
    hipMemsetAsync(c1, 0, (size_t)NBUK * 16 * sizeof(int), stream);
    place1_kernel<<<edge_blocks, TPB, 0, stream>>>(row, col, boff, c1, tmp, E);
    place2_kernel<<<NBUK, TPB, 0, stream>>>(tmp, boff, row_ptr, srow, N);

    // ---- Z0 = fp16(dis ⊙ emb)   (overwrites tmp — tmp is dead now)
    z0_kernel<<<z_blocks, TPB, 0, stream>>>(emb, dis, A, n);

    // ---- layer 1: out = emb + embs ; B = pre-scaled next state (fp16)
    spmm_kernel<0, true><<<spmm_blocks, TPB, 0, stream>>>(row_ptr, srow, dis, A, B,
                                                          out, emb, N);
    // ---- layer 2: out += embs ; A = next state
    spmm_kernel<1, true><<<spmm_blocks, TPB, 0, stream>>>(row_ptr, srow, dis, B, A,
                                                          out, emb, N);
    // ---- layer 3: out = (out + embs) * 0.25
    spmm_kernel<2, false><<<spmm_blocks, TPB, 0, stream>>>(row_ptr, srow, dis, A, nullptr,
                                                           out, emb, N);
}

// Round 8
// 522.231 us; speedup vs baseline: 1.6472x; 1.6472x over previous
//
#include <hip/hip_runtime.h>
#include <hip/hip_fp16.h>

#define D 64
constexpr int TPB = 256;
constexpr int VSHIFT = 9;            // 512 nodes per bucket
constexpr int VNODES = 1 << VSHIFT;  // 512
constexpr int CHUNK = 8192;          // edges per partition block
typedef unsigned short u16;

// ---------------- passA: per-chunk histogram over buckets --------------------
__global__ void passA_kernel(const int* __restrict__ col, int* __restrict__ H,
                             int E, int NBLK, int NBUK) {
    __shared__ int h[VNODES];        // NBUK <= 512
    int t = threadIdx.x, blk = blockIdx.x;
    for (int b = t; b < NBUK; b += TPB) h[b] = 0;
    __syncthreads();
    int base = blk * CHUNK, end = min(base + CHUNK, E);
    for (int i = base + t; i < end; i += TPB)
        atomicAdd(&h[col[i] >> VSHIFT], 1);
    __syncthreads();
    for (int b = t; b < NBUK; b += TPB) H[(size_t)b * NBLK + blk] = h[b];
}

// ---------------- scan stage 1: per-block inclusive scan + block sums --------
__global__ void scan1_kernel(const int* __restrict__ v, int* __restrict__ part,
                             int* __restrict__ bsum, int M) {
    __shared__ int s[TPB];
    int t = threadIdx.x;
    int i = blockIdx.x * TPB + t;
    int x0 = (i < M) ? v[i] : 0;
    s[t] = x0;
    __syncthreads();
    for (int off = 1; off < TPB; off <<= 1) {
        int x = (t >= off) ? s[t - off] : 0;
        __syncthreads();
        s[t] += x;
        __syncthreads();
    }
    if (i < M) part[i] = s[t];
    if (t == TPB - 1) bsum[blockIdx.x] = s[t];
}

// ---------------- scan stage 2: exclusive scan of block sums (single block) --
__global__ void scan2_kernel(const int* __restrict__ bsum, int* __restrict__ boff, int nb) {
    __shared__ int s[1024];
    int t = threadIdx.x;
    int v = (t < nb) ? bsum[t] : 0;
    s[t] = v;
    __syncthreads();
    for (int off = 1; off < 1024; off <<= 1) {
        int x = (t >= off) ? s[t - off] : 0;
        __syncthreads();
        s[t] += x;
        __syncthreads();
    }
    if (t < nb) boff[t] = s[t] - v;   // exclusive
}

// ---------------- scan stage 3: pos[i] = boff[blk] + part[i] - v[i] ----------
__global__ void scan3_kernel(const int* __restrict__ v, const int* __restrict__ part,
                             const int* __restrict__ boff, int* __restrict__ pos, int M) {
    int i = blockIdx.x * blockDim.x + threadIdx.x;
    if (i < M) pos[i] = boff[blockIdx.x] + part[i] - v[i];
}

// ---------------- passB: partition edges into bucket-sorted tmp --------------
// Each (block,bucket) run is a private contiguous stretch -> no line sharing.
__global__ void passB_kernel(const int* __restrict__ row, const int* __restrict__ col,
                             const int* __restrict__ pos, unsigned* __restrict__ tmp,
                             int E, int NBLK, int NBUK) {
    __shared__ int cur[VNODES];
    int t = threadIdx.x, blk = blockIdx.x;
    for (int b = t; b < NBUK; b += TPB) cur[b] = pos[(size_t)b * NBLK + blk];
    __syncthreads();
    int base = blk * CHUNK, end = min(base + CHUNK, E);
    for (int i = base + t; i < end; i += TPB) {
        int c = col[i];
        int p = atomicAdd(&cur[c >> VSHIFT], 1);
        tmp[p] = ((unsigned)(c & (VNODES - 1)) << 18) | (unsigned)row[i];
    }
}

// ---------------- passC: fused deg + dis + row_ptr + placement ---------------
// One block per bucket (512 nodes, ~13.7K edges). Counts in LDS, Blelloch-scans
// to node offsets, writes row_ptr/dis coalesced, places srow in a 55KB window.
__global__ void passC_kernel(const unsigned* __restrict__ tmp, const int* __restrict__ pos,
                             int* __restrict__ row_ptr, float* __restrict__ dis,
                             int* __restrict__ srow, int N, int E, int NBLK, int NBUK) {
    __shared__ int cnt[VNODES], sc[VNODES], cur[VNODES];
    __shared__ int se[2];
    int b = blockIdx.x, t = threadIdx.x;
    int nodeBase = b << VSHIFT;
    if (t == 0) {
        se[0] = pos[(size_t)b * NBLK];
        se[1] = (b + 1 < NBUK) ? pos[(size_t)(b + 1) * NBLK] : E;
    }
    cnt[t] = 0; cnt[t + 256] = 0;
    __syncthreads();
    int start = se[0], end = se[1];
    for (int i = start + t; i < end; i += TPB)
        atomicAdd(&cnt[tmp[i] >> 18], 1);
    __syncthreads();
    sc[t] = cnt[t]; sc[t + 256] = cnt[t + 256];
    __syncthreads();
    // Blelloch exclusive scan over 512 counts
    for (int off = 1; off < VNODES; off <<= 1) {
        int i = (t + 1) * (off << 1) - 1;
        if (i < VNODES) sc[i] += sc[i - off];
        __syncthreads();
    }
    if (t == 0) sc[VNODES - 1] = 0;
    __syncthreads();
    for (int off = VNODES / 2; off >= 1; off >>= 1) {
        int i = (t + 1) * (off << 1) - 1;
        if (i < VNODES) { int x = sc[i - off]; sc[i - off] = sc[i]; sc[i] += x; }
        __syncthreads();
    }
    for (int k = t; k < VNODES; k += TPB) {
        int rp = start + sc[k];
        cur[k] = rp;
        int node = nodeBase + k;
        if (node < N) {
            row_ptr[node] = rp;
            int d = cnt[k];
            dis[node] = (d > 0) ? rsqrtf((float)d) : 0.0f;
        }
    }
    if (b == 0 && t == 0) row_ptr[N] = E;
    __syncthreads();
    for (int i = start + t; i < end; i += TPB) {
        unsigned pk = tmp[i];
        int p = atomicAdd(&cur[pk >> 18], 1);
        srow[p] = (int)(pk & 0x3FFFFu);
    }
}

// ---------------- Z0 = fp16(dis ⊙ emb): one thread per element ---------------
__global__ void z0_kernel(const float* __restrict__ emb, const float* __restrict__ dis,
                          u16* __restrict__ z, int n) {
    int i = blockIdx.x * blockDim.x + threadIdx.x;
    if (i < n) {
        float d = dis[i >> 6];            // 64 floats per node
        z[i] = __half_as_ushort(__float2half_rn(d * emb[i]));
    }
}

// ---------------- CSR SpMM: one wave per destination node, lane = dim --------
// (verbatim from the passing round-6 kernel: 8-deep gather pipeline)
template <int MODE, bool WRITE_DST>
__global__ void spmm_kernel(const int* __restrict__ row_ptr, const int* __restrict__ srow,
                            const float* __restrict__ dis,
                            const u16* __restrict__ src, u16* __restrict__ dst,
                            float* __restrict__ out, const float* __restrict__ emb, int N) {
    int wave = (blockIdx.x * blockDim.x + threadIdx.x) >> 6;
    int lane = threadIdx.x & 63;
    if (wave >= N) return;
    int start = row_ptr[wave];
    int end   = row_ptr[wave + 1];
    float acc = 0.0f;
    for (int base = start; base < end; base += 64) {
        int mye = base + lane;
        int rr = (mye < end) ? srow[mye] : 0;   // coalesced edge-index load
        int cnt = min(64, end - base);
        int j = 0;
        for (; j + 8 <= cnt; j += 8) {
            int r0 = __shfl(rr, j + 0);
            int r1 = __shfl(rr, j + 1);
            int r2 = __shfl(rr, j + 2);
            int r3 = __shfl(rr, j + 3);
            int r4 = __shfl(rr, j + 4);
            int r5 = __shfl(rr, j + 5);
            int r6 = __shfl(rr, j + 6);
            int r7 = __shfl(rr, j + 7);
            u16 u0 = src[(size_t)r0 * D + lane];   // 8 independent row gathers
            u16 u1 = src[(size_t)r1 * D + lane];
            u16 u2 = src[(size_t)r2 * D + lane];
            u16 u3 = src[(size_t)r3 * D + lane];
            u16 u4 = src[(size_t)r4 * D + lane];
            u16 u5 = src[(size_t)r5 * D + lane];
            u16 u6 = src[(size_t)r6 * D + lane];
            u16 u7 = src[(size_t)r7 * D + lane];
            acc += __half2float(__ushort_as_half(u0));
            acc += __half2float(__ushort_as_half(u1));
            acc += __half2float(__ushort_as_half(u2));
            acc += __half2float(__ushort_as_half(u3));
            acc += __half2float(__ushort_as_half(u4));
            acc += __half2float(__ushort_as_half(u5));
            acc += __half2float(__ushort_as_half(u6));
            acc += __half2float(__ushort_as_half(u7));
        }
        for (; j < cnt; ++j) {
            int r = __shfl(rr, j);
            acc += __half2float(__ushort_as_half(src[(size_t)r * D + lane]));
        }
    }
    float dc = dis[wave];
    float embs = dc * acc;
    size_t o = (size_t)wave * D + lane;
    if (WRITE_DST) dst[o] = __half_as_ushort(__float2half_rn(dc * embs));
    if (MODE == 0)      out[o] = emb[o] + embs;
    else if (MODE == 1) out[o] += embs;
    else                out[o] = (out[o] + embs) * 0.25f;
}

extern "C" void kernel_launch(void* const* d_in, const int* in_sizes, int n_in,
                              void* d_out, int out_size, void* d_ws, size_t ws_size,
                              hipStream_t stream) {
    const int* edge = (const int*)d_in[0];
    const float* emb = (const float*)d_in[1];
    const int E = in_sizes[0] / 2;       // 4,000,000
    const int N = in_sizes[1] / D;       // 150,000
    float* out = (float*)d_out;

    const int* row = edge;
    const int* col = edge + E;

    const int NBLK = (E + CHUNK - 1) / CHUNK;           // 489
    const int NBUK = (N + VNODES - 1) >> VSHIFT;        // 293
    const int M = NBUK * NBLK;                          // 143,277
    const int nbH = (M + TPB - 1) / TPB;                // 560 (<=1024 for scan2)

    // workspace layout (tmp aliases A: dead before z0 writes A)
    u16*      A       = (u16*)d_ws;                     // N*64 fp16 (Z ping)
    u16*      B       = A + (size_t)N * D;              // N*64 fp16 (Z pong)
    int*      srow    = (int*)(B + (size_t)N * D);      // E ints
    int*      row_ptr = srow + E;                       // N+1 ints
    float*    dis     = (float*)(row_ptr + N + 1);      // N floats
    int*      H       = (int*)(dis + N);                // M ints
    int*      part    = H + M;                          // M ints
    int*      pos     = part + M;                       // M ints
    int*      bsum    = pos + M;                        // nbH ints
    int*      boff    = bsum + nbH;                     // nbH ints
    unsigned* tmp     = (unsigned*)A;                   // E uint32 (16MB <= A+B)

    const int n = N * D;
    const int z_blocks = (n + TPB - 1) / TPB;
    const int spmm_blocks = (N * 64 + TPB - 1) / TPB;   // 1 wave per node

    // ---- radix partition by destination bucket + fused CSR/deg/dis build
    passA_kernel<<<NBLK, TPB, 0, stream>>>(col, H, E, NBLK, NBUK);
    scan1_kernel<<<nbH, TPB, 0, stream>>>(H, part, bsum, M);
    scan2_kernel<<<1, 1024, 0, stream>>>(bsum, boff, nbH);
    scan3_kernel<<<nbH, TPB, 0, stream>>>(H, part, boff, pos, M);
    passB_kernel<<<NBLK, TPB, 0, stream>>>(row, col, pos, tmp, E, NBLK, NBUK);
    passC_kernel<<<NBUK, TPB, 0, stream>>>(tmp, pos, row_ptr, dis, srow, N, E, NBLK, NBUK);

    // ---- Z0 = fp16(dis ⊙ emb)   (overwrites tmp — dead now)
    z0_kernel<<<z_blocks, TPB, 0, stream>>>(emb, dis, A, n);

    // ---- layer 1: out = emb + embs ; B = pre-scaled next state (fp16)
    spmm_kernel<0, true><<<spmm_blocks, TPB, 0, stream>>>(row_ptr, srow, dis, A, B,
                                                          out, emb, N);
    // ---- layer 2: out += embs ; A = next state
    spmm_kernel<1, true><<<spmm_blocks, TPB, 0, stream>>>(row_ptr, srow, dis, B, A,
                                                          out, emb, N);
    // ---- layer 3: out = (out + embs) * 0.25
    spmm_kernel<2, false><<<spmm_blocks, TPB, 0, stream>>>(row_ptr, srow, dis, A, nullptr,
                                                           out, emb, N);
}

// Round 9
// 466.065 us; speedup vs baseline: 1.8457x; 1.1205x over previous
//
#include <hip/hip_runtime.h>
#include <hip/hip_fp16.h>

#define D 64
constexpr int TPB = 256;
constexpr int CTPB = 512;            // passC block size
constexpr int VSHIFT = 9;            // 512 nodes per bucket
constexpr int VNODES = 1 << VSHIFT;  // 512
constexpr int CHUNK = 8192;          // edges per partition block
typedef unsigned short u16;

__device__ inline unsigned h2pack(float a, float b) {
    unsigned lo = __half_as_ushort(__float2half_rn(a));
    unsigned hi = __half_as_ushort(__float2half_rn(b));
    return lo | (hi << 16);
}

// ---------------- passA: per-chunk histogram over buckets --------------------
__global__ void passA_kernel(const int* __restrict__ col, int* __restrict__ H,
                             int E, int NBLK, int NBUK) {
    __shared__ int h[VNODES];
    int t = threadIdx.x, blk = blockIdx.x;
    for (int b = t; b < NBUK; b += TPB) h[b] = 0;
    __syncthreads();
    int base = blk * CHUNK, end = min(base + CHUNK, E);
    for (int i = base + t; i < end; i += TPB)
        atomicAdd(&h[col[i] >> VSHIFT], 1);
    __syncthreads();
    for (int b = t; b < NBUK; b += TPB) H[(size_t)b * NBLK + blk] = h[b];
}

// ---------------- scan stage 1 -----------------------------------------------
__global__ void scan1_kernel(const int* __restrict__ v, int* __restrict__ part,
                             int* __restrict__ bsum, int M) {
    __shared__ int s[TPB];
    int t = threadIdx.x;
    int i = blockIdx.x * TPB + t;
    int x0 = (i < M) ? v[i] : 0;
    s[t] = x0;
    __syncthreads();
    for (int off = 1; off < TPB; off <<= 1) {
        int x = (t >= off) ? s[t - off] : 0;
        __syncthreads();
        s[t] += x;
        __syncthreads();
    }
    if (i < M) part[i] = s[t];
    if (t == TPB - 1) bsum[blockIdx.x] = s[t];
}

// ---------------- scan stage 2 -----------------------------------------------
__global__ void scan2_kernel(const int* __restrict__ bsum, int* __restrict__ boff, int nb) {
    __shared__ int s[1024];
    int t = threadIdx.x;
    int v = (t < nb) ? bsum[t] : 0;
    s[t] = v;
    __syncthreads();
    for (int off = 1; off < 1024; off <<= 1) {
        int x = (t >= off) ? s[t - off] : 0;
        __syncthreads();
        s[t] += x;
        __syncthreads();
    }
    if (t < nb) boff[t] = s[t] - v;   // exclusive
}

// ---------------- scan stage 3 -----------------------------------------------
__global__ void scan3_kernel(const int* __restrict__ v, const int* __restrict__ part,
                             const int* __restrict__ boff, int* __restrict__ pos, int M) {
    int i = blockIdx.x * blockDim.x + threadIdx.x;
    if (i < M) pos[i] = boff[blockIdx.x] + part[i] - v[i];
}

// ---------------- passB: partition edges into bucket-sorted tmp --------------
__global__ void passB_kernel(const int* __restrict__ row, const int* __restrict__ col,
                             const int* __restrict__ pos, unsigned* __restrict__ tmp,
                             int E, int NBLK, int NBUK) {
    __shared__ int cur[VNODES];
    int t = threadIdx.x, blk = blockIdx.x;
    for (int b = t; b < NBUK; b += TPB) cur[b] = pos[(size_t)b * NBLK + blk];
    __syncthreads();
    int base = blk * CHUNK, end = min(base + CHUNK, E);
    for (int i = base + t; i < end; i += TPB) {
        int c = col[i];
        int p = atomicAdd(&cur[c >> VSHIFT], 1);
        tmp[p] = ((unsigned)(c & (VNODES - 1)) << 18) | (unsigned)row[i];
    }
}

// ---------------- passC: fused deg + dis + row_ptr + placement + Z0 ----------
// One block (512 thr) per bucket of 512 nodes. After placing srow, also emits
// Z0 = fp16(dis ⊙ emb) for its nodes (deletes the separate z0 kernel).
__global__ void passC_kernel(const unsigned* __restrict__ tmp, const int* __restrict__ pos,
                             int* __restrict__ row_ptr, float* __restrict__ dis,
                             int* __restrict__ srow,
                             const float2* __restrict__ emb2, unsigned* __restrict__ z,
                             int N, int E, int NBLK, int NBUK) {
    __shared__ int cnt[VNODES], sc[VNODES], cur[VNODES];
    __shared__ int se[2];
    int b = blockIdx.x, t = threadIdx.x;
    int nodeBase = b << VSHIFT;
    if (t == 0) {
        se[0] = pos[(size_t)b * NBLK];
        se[1] = (b + 1 < NBUK) ? pos[(size_t)(b + 1) * NBLK] : E;
    }
    cnt[t] = 0;
    __syncthreads();
    int start = se[0], end = se[1];
    for (int i = start + t; i < end; i += CTPB)
        atomicAdd(&cnt[tmp[i] >> 18], 1);
    __syncthreads();
    sc[t] = cnt[t];
    __syncthreads();
    // Blelloch exclusive scan over 512 counts
    for (int off = 1; off < VNODES; off <<= 1) {
        int i = (t + 1) * (off << 1) - 1;
        if (i < VNODES) sc[i] += sc[i - off];
        __syncthreads();
    }
    if (t == 0) sc[VNODES - 1] = 0;
    __syncthreads();
    for (int off = VNODES / 2; off >= 1; off >>= 1) {
        int i = (t + 1) * (off << 1) - 1;
        if (i < VNODES) { int x = sc[i - off]; sc[i - off] = sc[i]; sc[i] += x; }
        __syncthreads();
    }
    {
        int rp = start + sc[t];
        cur[t] = rp;
        int node = nodeBase + t;
        if (node < N) {
            row_ptr[node] = rp;
            int d = cnt[t];
            dis[node] = (d > 0) ? rsqrtf((float)d) : 0.0f;
        }
    }
    if (b == 0 && t == 0) row_ptr[N] = E;
    __syncthreads();
    for (int i = start + t; i < end; i += CTPB) {
        unsigned pk = tmp[i];
        int p = atomicAdd(&cur[pk >> 18], 1);
        srow[p] = (int)(pk & 0x3FFFFu);
    }
    // Z0 for this bucket's nodes: coalesced float2 reads / dword writes
    for (int i = t; i < (VNODES << 5); i += CTPB) {
        int k = i >> 5;
        int node = nodeBase + k;
        if (node < N) {
            int d = cnt[k];
            float dv = (d > 0) ? rsqrtf((float)d) : 0.0f;
            size_t o = (size_t)node * 32 + (i & 31);
            float2 x = emb2[o];
            z[o] = h2pack(dv * x.x, dv * x.y);
        }
    }
}

// ---------------- CSR SpMM: two nodes per wave, dword fp16x2 loads -----------
// Half-wave h (32 lanes) independently handles node 2*wave+h: lane sub=lane&31
// covers dims (2*sub, 2*sub+1). No cross-half combine; each half epilogues its
// own node. 8-deep load pipeline retained.
template <int MODE, bool WRITE_DST>
__global__ void spmm_kernel(const int* __restrict__ row_ptr, const int* __restrict__ srow,
                            const float* __restrict__ dis,
                            const unsigned* __restrict__ src, unsigned* __restrict__ dst,
                            float2* __restrict__ out2, const float2* __restrict__ emb2,
                            int N) {
    int wave = (blockIdx.x * blockDim.x + threadIdx.x) >> 6;
    int lane = threadIdx.x & 63;
    int half = lane >> 5;
    int sub  = lane & 31;
    int node = 2 * wave + half;
    if (node >= N) return;
    int start = row_ptr[node];
    int end   = row_ptr[node + 1];
    float a0 = 0.0f, a1 = 0.0f;
    int hb = half << 5;
    for (int base = start; base < end; base += 32) {
        int mye = base + sub;
        int rr = (mye < end) ? srow[mye] : 0;   // 128B coalesced per half
        int cnt = min(32, end - base);
        int j = 0;
        for (; j + 8 <= cnt; j += 8) {
            int r0 = __shfl(rr, hb + j + 0);
            int r1 = __shfl(rr, hb + j + 1);
            int r2 = __shfl(rr, hb + j + 2);
            int r3 = __shfl(rr, hb + j + 3);
            int r4 = __shfl(rr, hb + j + 4);
            int r5 = __shfl(rr, hb + j + 5);
            int r6 = __shfl(rr, hb + j + 6);
            int r7 = __shfl(rr, hb + j + 7);
            unsigned u0 = src[(size_t)r0 * 32 + sub];   // 8 independent row gathers
            unsigned u1 = src[(size_t)r1 * 32 + sub];
            unsigned u2 = src[(size_t)r2 * 32 + sub];
            unsigned u3 = src[(size_t)r3 * 32 + sub];
            unsigned u4 = src[(size_t)r4 * 32 + sub];
            unsigned u5 = src[(size_t)r5 * 32 + sub];
            unsigned u6 = src[(size_t)r6 * 32 + sub];
            unsigned u7 = src[(size_t)r7 * 32 + sub];
            a0 += __half2float(__ushort_as_half((u16)(u0 & 0xffff)));
            a1 += __half2float(__ushort_as_half((u16)(u0 >> 16)));
            a0 += __half2float(__ushort_as_half((u16)(u1 & 0xffff)));
            a1 += __half2float(__ushort_as_half((u16)(u1 >> 16)));
            a0 += __half2float(__ushort_as_half((u16)(u2 & 0xffff)));
            a1 += __half2float(__ushort_as_half((u16)(u2 >> 16)));
            a0 += __half2float(__ushort_as_half((u16)(u3 & 0xffff)));
            a1 += __half2float(__ushort_as_half((u16)(u3 >> 16)));
            a0 += __half2float(__ushort_as_half((u16)(u4 & 0xffff)));
            a1 += __half2float(__ushort_as_half((u16)(u4 >> 16)));
            a0 += __half2float(__ushort_as_half((u16)(u5 & 0xffff)));
            a1 += __half2float(__ushort_as_half((u16)(u5 >> 16)));
            a0 += __half2float(__ushort_as_half((u16)(u6 & 0xffff)));
            a1 += __half2float(__ushort_as_half((u16)(u6 >> 16)));
            a0 += __half2float(__ushort_as_half((u16)(u7 & 0xffff)));
            a1 += __half2float(__ushort_as_half((u16)(u7 >> 16)));
        }
        for (; j < cnt; ++j) {
            int r = __shfl(rr, hb + j);
            unsigned u = src[(size_t)r * 32 + sub];
            a0 += __half2float(__ushort_as_half((u16)(u & 0xffff)));
            a1 += __half2float(__ushort_as_half((u16)(u >> 16)));
        }
    }
    float dc = dis[node];
    float e0 = dc * a0, e1 = dc * a1;
    size_t o = (size_t)node * 32 + sub;
    if (WRITE_DST) dst[o] = h2pack(dc * e0, dc * e1);   // pre-scaled next state
    float2 cur;
    if (MODE == 0)      { cur = emb2[o]; cur.x += e0; cur.y += e1; }
    else if (MODE == 1) { cur = out2[o]; cur.x += e0; cur.y += e1; }
    else                { cur = out2[o]; cur.x = (cur.x + e0) * 0.25f;
                                         cur.y = (cur.y + e1) * 0.25f; }
    out2[o] = cur;
}

extern "C" void kernel_launch(void* const* d_in, const int* in_sizes, int n_in,
                              void* d_out, int out_size, void* d_ws, size_t ws_size,
                              hipStream_t stream) {
    const int* edge = (const int*)d_in[0];
    const float* emb = (const float*)d_in[1];
    const int E = in_sizes[0] / 2;       // 4,000,000
    const int N = in_sizes[1] / D;       // 150,000
    float2* out2 = (float2*)d_out;

    const int* row = edge;
    const int* col = edge + E;

    const int NBLK = (E + CHUNK - 1) / CHUNK;           // 489
    const int NBUK = (N + VNODES - 1) >> VSHIFT;        // 293
    const int M = NBUK * NBLK;                          // 143,277
    const int nbH = (M + TPB - 1) / TPB;                // 560 (<=1024 for scan2)

    // workspace layout (~73.4 MB; no aliasing)
    unsigned* A       = (unsigned*)d_ws;                // N*32 dwords (fp16x2 Z ping)
    unsigned* B       = A + (size_t)N * 32;             // N*32 dwords (Z pong)
    int*      srow    = (int*)(B + (size_t)N * 32);     // E ints
    int*      row_ptr = srow + E;                       // N+1 ints
    float*    dis     = (float*)(row_ptr + N + 1);      // N floats
    int*      H       = (int*)(dis + N);                // M ints
    int*      part    = H + M;                          // M ints
    int*      pos     = part + M;                       // M ints
    int*      bsum    = pos + M;                        // nbH ints
    int*      boff    = bsum + nbH;                     // nbH ints
    unsigned* tmp     = (unsigned*)(boff + nbH);        // E dwords (16 MB)

    const int spmm_blocks = (((N + 1) / 2) * 64 + TPB - 1) / TPB;   // 2 nodes/wave

    // ---- radix partition by destination bucket + fused CSR/deg/dis/Z0 build
    passA_kernel<<<NBLK, TPB, 0, stream>>>(col, H, E, NBLK, NBUK);
    scan1_kernel<<<nbH, TPB, 0, stream>>>(H, part, bsum, M);
    scan2_kernel<<<1, 1024, 0, stream>>>(bsum, boff, nbH);
    scan3_kernel<<<nbH, TPB, 0, stream>>>(H, part, boff, pos, M);
    passB_kernel<<<NBLK, TPB, 0, stream>>>(row, col, pos, tmp, E, NBLK, NBUK);
    passC_kernel<<<NBUK, CTPB, 0, stream>>>(tmp, pos, row_ptr, dis, srow,
                                            (const float2*)emb, A, N, E, NBLK, NBUK);

    // ---- layer 1: out = emb + embs ; B = pre-scaled next state (fp16)
    spmm_kernel<0, true><<<spmm_blocks, TPB, 0, stream>>>(row_ptr, srow, dis, A, B,
                                                          out2, (const float2*)emb, N);
    // ---- layer 2: out += embs ; A = next state
    spmm_kernel<1, true><<<spmm_blocks, TPB, 0, stream>>>(row_ptr, srow, dis, B, A,
                                                          out2, (const float2*)emb, N);
    // ---- layer 3: out = (out + embs) * 0.25
    spmm_kernel<2, false><<<spmm_blocks, TPB, 0, stream>>>(row_ptr, srow, dis, A, nullptr,
                                                           out2, (const float2*)emb, N);
}